// Round 3
// baseline (2043.702 us; speedup 1.0000x reference)
//
#include <hip/hip_runtime.h>

#define EPSF 1e-8f
#define RCUT 4.8f
#define NB 64
#define NSEL 20

#define FOR16(OP) OP(0) OP(1) OP(2) OP(3) OP(4) OP(5) OP(6) OP(7) \
                  OP(8) OP(9) OP(10) OP(11) OP(12) OP(13) OP(14) OP(15)

__device__ __forceinline__ float fast_tanh(float x) {
    float e = __expf(2.0f * x);
    return 1.0f - __fdividef(2.0f, e + 1.0f);
}

// ---------------- Kernel A: norms + select 20 nearest (sorted) ----------------
extern "C" __global__ void __launch_bounds__(256)
sel_kernel(const float* __restrict__ dr, const float* __restrict__ W0,
           const float* __restrict__ b0,
           float* __restrict__ ws_R, float* __restrict__ ws_fc,
           float* __restrict__ ws_F, int* __restrict__ ws_idx,
           float* __restrict__ ws_ndn, float* __restrict__ ws_W0T)
{
    __shared__ float R_s[256];
    const int t = threadIdx.x;
    const int g = t >> 6;       // which b within block (0..3)
    const int j = t & 63;       // neighbor id
    const int b = blockIdx.x * 4 + g;

    const float* p = dr + ((size_t)b * NB + j) * 3;
    float x = p[0] + EPSF, y = p[1] + EPSF, z = p[2] + EPSF;
    float R = sqrtf(x * x + y * y + z * z);
    R_s[t] = R;
    __syncthreads();

    // stable rank: count (Rk < R) or (Rk == R and k < j)
    int rank = 0;
    const float* grp = R_s + g * 64;
    #pragma unroll 8
    for (int k = 0; k < 64; ++k) {
        float Rk = grp[k];
        rank += (Rk < R || (Rk == R && k < j)) ? 1 : 0;
    }

    float fc = 0.0f;
    if (rank < NSEL) {
        fc = (R > RCUT) ? 0.0f
                        : (0.5f * __cosf(3.14159265358979323846f * R / RCUT) + 0.5f);
        size_t o = (size_t)b * NSEL + rank;
        ws_R[o]  = R;
        ws_fc[o] = fc;
        ws_idx[o] = j;
        float inv = 1.0f / R;
        ws_ndn[o * 3 + 0] = x * inv;
        ws_ndn[o * 3 + 1] = y * inv;
        ws_ndn[o * 3 + 2] = z * inv;
    }

    // F[b] = sum of selected fc over this wave (each group is exactly one wave)
    float F = fc;
    for (int off = 32; off > 0; off >>= 1) F += __shfl_xor(F, off, 64);
    if (j == 0) ws_F[b] = F;

    // one-time W0^T pack, padded to 16 with b0 in slot 15 (block 0 only)
    if (blockIdx.x == 0) {
        for (int i = t; i < 64 * 16; i += 256) {
            int jj = i >> 4, k = i & 15;
            ws_W0T[i] = (k < 15) ? W0[k * 64 + jj] : b0[jj];
        }
    }
}

// ---------------- Kernel B: 4 lanes per pair, MLP fwd + analytic bwd ----------
extern "C" __global__ void __launch_bounds__(320, 1)
energy_kernel(const float* __restrict__ orientation, const float* __restrict__ n_or,
              const float* __restrict__ W0T,
              const float* __restrict__ W1, const float* __restrict__ b1,
              const float* __restrict__ W2, const float* __restrict__ b2p,
              const float* __restrict__ f1, const float* __restrict__ f2,
              const float* __restrict__ ws_R, const float* __restrict__ ws_fc,
              const float* __restrict__ ws_F, const int* __restrict__ ws_idx,
              const float* __restrict__ ws_ndn,
              float* __restrict__ out_force, float* __restrict__ out_torque,
              float* __restrict__ out_energy)
{
    __shared__ float p_s[80];
    __shared__ float red[80][13];
    __shared__ float G[4][12];

    const int t   = threadIdx.x;
    const int pl  = t >> 2;        // pair slot in block (0..79)
    const int sub = t & 3;         // lane within pair-quad
    const int bl  = pl / 20;       // local b (0..3)
    const int n   = pl % 20;
    const int b   = blockIdx.x * 4 + bl;
    const size_t o = (size_t)b * NSEL + n;
    const int i_base = sub * 16;   // owned layer-2 units
    const int j_base = sub * 16;   // owned layer-1 units

    const float R  = ws_R[o];
    const float F  = ws_F[b];
    const int  idx = ws_idx[o];
    const float nd0 = ws_ndn[o * 3 + 0];
    const float nd1 = ws_ndn[o * 3 + 1];
    const float nd2 = ws_ndn[o * 3 + 2];

    // ---- feature build (straight-line, named scalars) ----
    float ft0, ft1, ft2, ft3, ft4, ft5, ft6, ft7, ft8, ft9, ft10, ft11, ft12, ft13, ft14;
    {
        const float* Op = orientation + (size_t)b * 9;
        float o0 = Op[0], o1 = Op[1], o2 = Op[2], o3 = Op[3], o4 = Op[4],
              o5 = Op[5], o6 = Op[6], o7 = Op[7], o8 = Op[8];
        const float* Np = n_or + ((size_t)b * NB + idx) * 9;
        float q0 = Np[0], q1 = Np[1], q2 = Np[2], q3 = Np[3], q4 = Np[4],
              q5 = Np[5], q6 = Np[6], q7 = Np[7], q8 = Np[8];

        ft0 = nd0 * o0 + nd1 * o3 + nd2 * o6;
        ft1 = nd0 * o1 + nd1 * o4 + nd2 * o7;
        ft2 = nd0 * o2 + nd1 * o5 + nd2 * o8;
        ft3 = nd0 * q0 + nd1 * q3 + nd2 * q6;
        ft4 = nd0 * q1 + nd1 * q4 + nd2 * q7;
        ft5 = nd0 * q2 + nd1 * q5 + nd2 * q8;
        ft6  = o0 * q0 + o3 * q3 + o6 * q6;
        ft7  = o0 * q1 + o3 * q4 + o6 * q7;
        ft8  = o0 * q2 + o3 * q5 + o6 * q8;
        ft9  = o1 * q0 + o4 * q3 + o7 * q6;
        ft10 = o1 * q1 + o4 * q4 + o7 * q7;
        ft11 = o1 * q2 + o4 * q5 + o7 * q8;
        ft12 = o2 * q0 + o5 * q3 + o8 * q6;
        ft13 = o2 * q1 + o5 * q4 + o8 * q7;
        ft14 = o2 * q2 + o5 * q5 + o8 * q8;
    }

    // ---- forward layer 1: own 16 hidden units ----
#define DECL_H(m) float h_##m;
    FOR16(DECL_H)
#undef DECL_H

#define L1(m) { \
    const float4* w = (const float4*)(W0T + ((j_base + m) << 4)); \
    float4 wa = w[0], wb = w[1], wc = w[2], wd = w[3]; \
    float za = wd.w, zb = 0.f; /* b0 packed in slot 15 */ \
    za = fmaf(ft0,  wa.x, za); zb = fmaf(ft1,  wa.y, zb); \
    za = fmaf(ft2,  wa.z, za); zb = fmaf(ft3,  wa.w, zb); \
    za = fmaf(ft4,  wb.x, za); zb = fmaf(ft5,  wb.y, zb); \
    za = fmaf(ft6,  wb.z, za); zb = fmaf(ft7,  wb.w, zb); \
    za = fmaf(ft8,  wc.x, za); zb = fmaf(ft9,  wc.y, zb); \
    za = fmaf(ft10, wc.z, za); zb = fmaf(ft11, wc.w, zb); \
    za = fmaf(ft12, wd.x, za); zb = fmaf(ft13, wd.y, zb); \
    za = fmaf(ft14, wd.z, za); \
    h_##m = fast_tanh(za + zb); }
    FOR16(L1)
#undef L1

    // ---- forward layer 2: own 16 accumulators, h1 broadcast over the quad ----
    float a_0, a_1, a_2, a_3, a_4, a_5, a_6, a_7,
          a_8, a_9, a_10, a_11, a_12, a_13, a_14, a_15;
    {
        const float4* bv = (const float4*)(b1 + i_base);
        float4 ba = bv[0], bb4 = bv[1], bc = bv[2], bd = bv[3];
        a_0 = ba.x;  a_1 = ba.y;  a_2 = ba.z;  a_3 = ba.w;
        a_4 = bb4.x; a_5 = bb4.y; a_6 = bb4.z; a_7 = bb4.w;
        a_8 = bc.x;  a_9 = bc.y;  a_10 = bc.z; a_11 = bc.w;
        a_12 = bd.x; a_13 = bd.y; a_14 = bd.z; a_15 = bd.w;
    }

#define L2(m) { \
    float hh = __shfl(h_##m, jq, 4); \
    const float4* w = (const float4*)(W1 + ((jq * 16 + m) << 6) + i_base); \
    float4 wa = w[0], wb = w[1], wc = w[2], wd = w[3]; \
    a_0  = fmaf(hh, wa.x, a_0);  a_1  = fmaf(hh, wa.y, a_1); \
    a_2  = fmaf(hh, wa.z, a_2);  a_3  = fmaf(hh, wa.w, a_3); \
    a_4  = fmaf(hh, wb.x, a_4);  a_5  = fmaf(hh, wb.y, a_5); \
    a_6  = fmaf(hh, wb.z, a_6);  a_7  = fmaf(hh, wb.w, a_7); \
    a_8  = fmaf(hh, wc.x, a_8);  a_9  = fmaf(hh, wc.y, a_9); \
    a_10 = fmaf(hh, wc.z, a_10); a_11 = fmaf(hh, wc.w, a_11); \
    a_12 = fmaf(hh, wd.x, a_12); a_13 = fmaf(hh, wd.y, a_13); \
    a_14 = fmaf(hh, wd.z, a_14); a_15 = fmaf(hh, wd.w, a_15); }
    #pragma unroll
    for (int jq = 0; jq < 4; ++jq) {
        FOR16(L2)
    }
#undef L2

    // ---- h2, z3 (quad-reduced), scalar tail ----
    const float4* w2v = (const float4*)(W2 + i_base);
    float4 w2a = w2v[0], w2b = w2v[1], w2c = w2v[2], w2d = w2v[3];
#define H2(m) a_##m = fast_tanh(a_##m);
    FOR16(H2)
#undef H2
    float z3a = 0.f, z3b = 0.f;
    z3a = fmaf(a_0,  w2a.x, z3a); z3b = fmaf(a_1,  w2a.y, z3b);
    z3a = fmaf(a_2,  w2a.z, z3a); z3b = fmaf(a_3,  w2a.w, z3b);
    z3a = fmaf(a_4,  w2b.x, z3a); z3b = fmaf(a_5,  w2b.y, z3b);
    z3a = fmaf(a_6,  w2b.z, z3a); z3b = fmaf(a_7,  w2b.w, z3b);
    z3a = fmaf(a_8,  w2c.x, z3a); z3b = fmaf(a_9,  w2c.y, z3b);
    z3a = fmaf(a_10, w2c.z, z3a); z3b = fmaf(a_11, w2c.w, z3b);
    z3a = fmaf(a_12, w2d.x, z3a); z3b = fmaf(a_13, w2d.y, z3b);
    z3a = fmaf(a_14, w2d.z, z3a); z3b = fmaf(a_15, w2d.w, z3b);
    float z3 = z3a + z3b;
    z3 += __shfl_xor(z3, 1, 4);
    z3 += __shfl_xor(z3, 2, 4);
    const float enc = fast_tanh(z3 + b2p[0]);
    const float x = R - (enc * enc + EPSF);

    const float lx = __logf(x);
    float psum = 0.f, csum = 0.f;
    #pragma unroll
    for (int q = 0; q < 3; ++q) {
        float aq = f1[q] * f1[q] + EPSF;
        float cq = f2[q] * f2[q] + EPSF;
        float tq = __expf(-cq * (__logf(aq) + lx));   // (a*x)^(-c)
        psum += tq;
        csum = fmaf(cq, tq, csum);
    }
    const float dpdx = -__fdividef(csum, x);

    // ---- energy output ----
    if (sub == 0) p_s[pl] = psum;
    __syncthreads();
    if (t < 80) {
        int bb = t / 20;
        float S = 0.f;
        #pragma unroll
        for (int m = 0; m < 20; ++m) S += p_s[bb * 20 + m];
        size_t oo = ((size_t)(blockIdx.x * 4 + bb)) * NSEL + (t % 20);
        out_energy[oo] = S * ws_fc[oo];
    }

    // ---- backward ----
    const float dz3 = F * dpdx * (-2.f * enc) * (1.f - enc * enc);
    a_0  = dz3 * w2a.x * (1.f - a_0 * a_0);
    a_1  = dz3 * w2a.y * (1.f - a_1 * a_1);
    a_2  = dz3 * w2a.z * (1.f - a_2 * a_2);
    a_3  = dz3 * w2a.w * (1.f - a_3 * a_3);
    a_4  = dz3 * w2b.x * (1.f - a_4 * a_4);
    a_5  = dz3 * w2b.y * (1.f - a_5 * a_5);
    a_6  = dz3 * w2b.z * (1.f - a_6 * a_6);
    a_7  = dz3 * w2b.w * (1.f - a_7 * a_7);
    a_8  = dz3 * w2c.x * (1.f - a_8 * a_8);
    a_9  = dz3 * w2c.y * (1.f - a_9 * a_9);
    a_10 = dz3 * w2c.z * (1.f - a_10 * a_10);
    a_11 = dz3 * w2c.w * (1.f - a_11 * a_11);
    a_12 = dz3 * w2d.x * (1.f - a_12 * a_12);
    a_13 = dz3 * w2d.y * (1.f - a_13 * a_13);
    a_14 = dz3 * w2d.z * (1.f - a_14 * a_14);
    a_15 = dz3 * w2d.w * (1.f - a_15 * a_15);

    // dh1 for own 16 j's: rotate partials around the quad
#define DECL_DH(m) float dh_##m = 0.f;
    FOR16(DECL_DH)
#undef DECL_DH

#define DH(m) { \
    const float4* w = (const float4*)(W1 + ((jsrc * 16 + m) << 6) + i_base); \
    float4 wa = w[0], wb = w[1], wc = w[2], wd = w[3]; \
    float pa = 0.f, pb = 0.f; \
    pa = fmaf(a_0,  wa.x, pa); pb = fmaf(a_1,  wa.y, pb); \
    pa = fmaf(a_2,  wa.z, pa); pb = fmaf(a_3,  wa.w, pb); \
    pa = fmaf(a_4,  wb.x, pa); pb = fmaf(a_5,  wb.y, pb); \
    pa = fmaf(a_6,  wb.z, pa); pb = fmaf(a_7,  wb.w, pb); \
    pa = fmaf(a_8,  wc.x, pa); pb = fmaf(a_9,  wc.y, pb); \
    pa = fmaf(a_10, wc.z, pa); pb = fmaf(a_11, wc.w, pb); \
    pa = fmaf(a_12, wd.x, pa); pb = fmaf(a_13, wd.y, pb); \
    pa = fmaf(a_14, wd.z, pa); pb = fmaf(a_15, wd.w, pb); \
    dh_##m += __shfl_xor(pa + pb, r, 4); }
    #pragma unroll
    for (int r = 0; r < 4; ++r) {
        const int jsrc = sub ^ r;
        FOR16(DH)
    }
#undef DH

    // dz1 -> dfeat (own 16 j's), named scalars
    float df0 = 0.f, df1 = 0.f, df2 = 0.f, df3 = 0.f, df4 = 0.f,
          df5 = 0.f, df6 = 0.f, df7 = 0.f, df8 = 0.f, df9 = 0.f,
          df10 = 0.f, df11 = 0.f, df12 = 0.f, df13 = 0.f, df14 = 0.f;
#define DF(m) { \
    float dz1 = dh_##m * (1.f - h_##m * h_##m); \
    const float4* w = (const float4*)(W0T + ((j_base + m) << 4)); \
    float4 wa = w[0], wb = w[1], wc = w[2], wd = w[3]; \
    df0  = fmaf(dz1, wa.x, df0);  df1  = fmaf(dz1, wa.y, df1); \
    df2  = fmaf(dz1, wa.z, df2);  df3  = fmaf(dz1, wa.w, df3); \
    df4  = fmaf(dz1, wb.x, df4);  df5  = fmaf(dz1, wb.y, df5); \
    df6  = fmaf(dz1, wb.z, df6);  df7  = fmaf(dz1, wb.w, df7); \
    df8  = fmaf(dz1, wc.x, df8);  df9  = fmaf(dz1, wc.y, df9); \
    df10 = fmaf(dz1, wc.z, df10); df11 = fmaf(dz1, wc.w, df11); \
    df12 = fmaf(dz1, wd.x, df12); df13 = fmaf(dz1, wd.y, df13); \
    df14 = fmaf(dz1, wd.z, df14); }
    FOR16(DF)
#undef DF

    // reduce dfeat across the quad (butterfly)
#define REDD(k) df##k += __shfl_xor(df##k, 1, 4); df##k += __shfl_xor(df##k, 2, 4);
    REDD(0) REDD(1) REDD(2) REDD(3) REDD(4) REDD(5) REDD(6) REDD(7)
    REDD(8) REDD(9) REDD(10) REDD(11) REDD(12) REDD(13) REDD(14)
#undef REDD

    // ---- epilogue: reload O/Nr (volatile keeps earlier live ranges short) ----
    float o0, o1, o2, o3, o4, o5, o6, o7, o8;
    float q0, q1, q2, q3, q4, q5, q6, q7, q8;
    {
        const volatile float* Ov = orientation + (size_t)b * 9;
        o0 = Ov[0]; o1 = Ov[1]; o2 = Ov[2]; o3 = Ov[3]; o4 = Ov[4];
        o5 = Ov[5]; o6 = Ov[6]; o7 = Ov[7]; o8 = Ov[8];
        const volatile float* Nv = n_or + ((size_t)b * NB + idx) * 9;
        q0 = Nv[0]; q1 = Nv[1]; q2 = Nv[2]; q3 = Nv[3]; q4 = Nv[4];
        q5 = Nv[5]; q6 = Nv[6]; q7 = Nv[7]; q8 = Nv[8];
    }

    float g0 = df0 * o0 + df1 * o1 + df2 * o2 + df3 * q0 + df4 * q1 + df5 * q2;
    float g1 = df0 * o3 + df1 * o4 + df2 * o5 + df3 * q3 + df4 * q4 + df5 * q5;
    float g2 = df0 * o6 + df1 * o7 + df2 * o8 + df3 * q6 + df4 * q7 + df5 * q8;

    float gO00 = df0 * nd0 + (df6 * q0 + df7 * q1 + df8 * q2);
    float gO01 = df1 * nd0 + (df9 * q0 + df10 * q1 + df11 * q2);
    float gO02 = df2 * nd0 + (df12 * q0 + df13 * q1 + df14 * q2);
    float gO10 = df0 * nd1 + (df6 * q3 + df7 * q4 + df8 * q5);
    float gO11 = df1 * nd1 + (df9 * q3 + df10 * q4 + df11 * q5);
    float gO12 = df2 * nd1 + (df12 * q3 + df13 * q4 + df14 * q5);
    float gO20 = df0 * nd2 + (df6 * q6 + df7 * q7 + df8 * q8);
    float gO21 = df1 * nd2 + (df9 * q6 + df10 * q7 + df11 * q8);
    float gO22 = df2 * nd2 + (df12 * q6 + df13 * q7 + df14 * q8);

    if (sub == 0) {
        red[pl][0] = g0;  red[pl][1] = g1;  red[pl][2] = g2;
        red[pl][3] = gO00; red[pl][4] = gO01; red[pl][5] = gO02;
        red[pl][6] = gO10; red[pl][7] = gO11; red[pl][8] = gO12;
        red[pl][9] = gO20; red[pl][10] = gO21; red[pl][11] = gO22;
    }
    __syncthreads();

    for (int i = t; i < 4 * 12; i += 320) {
        int bb = i / 12, q = i % 12;
        float s = 0.f;
        #pragma unroll
        for (int m = 0; m < 20; ++m) s += red[bb * 20 + m][q];
        G[bb][q] = s;
    }
    __syncthreads();

    if (t < 4) {
        const int gb = blockIdx.x * 4 + t;
        out_force[gb * 3 + 0] = G[t][0];
        out_force[gb * 3 + 1] = G[t][1];
        out_force[gb * 3 + 2] = G[t][2];
        const float* Og = orientation + (size_t)gb * 9;
        float t0 = 0.f, t1 = 0.f, t2 = 0.f;
        #pragma unroll
        for (int jj = 0; jj < 3; ++jj) {
            float u0 = G[t][3 + 0 * 3 + jj], u1 = G[t][3 + 1 * 3 + jj], u2 = G[t][3 + 2 * 3 + jj];
            float v0 = Og[0 * 3 + jj], v1 = Og[1 * 3 + jj], v2 = Og[2 * 3 + jj];
            t0 += u1 * v2 - u2 * v1;
            t1 += u2 * v0 - u0 * v2;
            t2 += u0 * v1 - u1 * v0;
        }
        out_torque[gb * 3 + 0] = t0;
        out_torque[gb * 3 + 1] = t1;
        out_torque[gb * 3 + 2] = t2;
    }
}

extern "C" void kernel_launch(void* const* d_in, const int* in_sizes, int n_in,
                              void* d_out, int out_size, void* d_ws, size_t ws_size,
                              hipStream_t stream) {
    const float* dr            = (const float*)d_in[0];
    const float* orientation   = (const float*)d_in[1];
    const float* n_orientation = (const float*)d_in[2];
    const float* W0 = (const float*)d_in[3];
    const float* b0 = (const float*)d_in[4];
    const float* W1 = (const float*)d_in[5];
    const float* b1 = (const float*)d_in[6];
    const float* W2 = (const float*)d_in[7];
    const float* b2 = (const float*)d_in[8];
    const float* f1 = (const float*)d_in[9];
    const float* f2 = (const float*)d_in[10];

    const int B = in_sizes[0] / (NB * 3);   // 32768

    float* out = (float*)d_out;
    float* out_force  = out;
    float* out_torque = out + (size_t)3 * B;
    float* out_energy = out + (size_t)6 * B;

    float* ws_R   = (float*)d_ws;                       // B*20
    float* ws_fc  = ws_R  + (size_t)B * NSEL;           // B*20
    float* ws_F   = ws_fc + (size_t)B * NSEL;           // B
    int*   ws_idx = (int*)(ws_F + B);                   // B*20
    float* ws_ndn = (float*)(ws_idx + (size_t)B * NSEL);// B*20*3
    float* ws_W0T = ws_ndn + (size_t)B * NSEL * 3;      // 64*16 padded, b0 in slot 15

    sel_kernel<<<B / 4, 256, 0, stream>>>(dr, W0, b0, ws_R, ws_fc, ws_F, ws_idx, ws_ndn, ws_W0T);
    energy_kernel<<<B / 4, 320, 0, stream>>>(orientation, n_orientation,
                                             ws_W0T, W1, b1, W2, b2, f1, f2,
                                             ws_R, ws_fc, ws_F, ws_idx, ws_ndn,
                                             out_force, out_torque, out_energy);
}

// Round 4
// 646.780 us; speedup vs baseline: 3.1598x; 3.1598x over previous
//
#include <hip/hip_runtime.h>

#define EPSF 1e-8f
#define RCUT 4.8f
#define NB 64
#define NSEL 20

__device__ __forceinline__ float fast_tanh(float x) {
    float e = __expf(2.0f * x);
    return 1.0f - __fdividef(2.0f, e + 1.0f);
}

// ---------------- Kernel A: norms + select 20 nearest (sorted) ----------------
extern "C" __global__ void __launch_bounds__(256)
sel_kernel(const float* __restrict__ dr, const float* __restrict__ W0,
           float* __restrict__ ws_R, float* __restrict__ ws_fc,
           float* __restrict__ ws_F, int* __restrict__ ws_idx,
           float* __restrict__ ws_ndn, float* __restrict__ ws_W0T)
{
    __shared__ float R_s[256];
    const int t = threadIdx.x;
    const int g = t >> 6;       // which b within block (0..3)
    const int j = t & 63;       // neighbor id
    const int b = blockIdx.x * 4 + g;

    const float* p = dr + ((size_t)b * NB + j) * 3;
    float x = p[0] + EPSF, y = p[1] + EPSF, z = p[2] + EPSF;
    float R = sqrtf(x * x + y * y + z * z);
    R_s[t] = R;
    __syncthreads();

    // stable rank: count (Rk < R) or (Rk == R and k < j)
    int rank = 0;
    const float* grp = R_s + g * 64;
    #pragma unroll 8
    for (int k = 0; k < 64; ++k) {
        float Rk = grp[k];
        rank += (Rk < R || (Rk == R && k < j)) ? 1 : 0;
    }

    float fc = 0.0f;
    if (rank < NSEL) {
        fc = (R > RCUT) ? 0.0f
                        : (0.5f * __cosf(3.14159265358979323846f * R / RCUT) + 0.5f);
        size_t o = (size_t)b * NSEL + rank;
        ws_R[o]  = R;
        ws_fc[o] = fc;
        ws_idx[o] = j;
        float inv = 1.0f / R;
        ws_ndn[o * 3 + 0] = x * inv;
        ws_ndn[o * 3 + 1] = y * inv;
        ws_ndn[o * 3 + 2] = z * inv;
    }

    // F[b] = sum of selected fc over this wave (each group is exactly one wave)
    float F = fc;
    for (int off = 32; off > 0; off >>= 1) F += __shfl_xor(F, off, 64);
    if (j == 0) ws_F[b] = F;

    // one-time W0 transpose (block 0 only; A always runs before B on the stream)
    if (blockIdx.x == 0) {
        for (int i = t; i < 15 * 64; i += 256) {
            int k = i >> 6, jj = i & 63;
            ws_W0T[jj * 15 + k] = W0[i];
        }
    }
}

// ---------------- Kernel B: per-pair MLP fwd + analytic bwd ----------------
// launch_bounds(320,3): cap ~170 regs so acc[64] stays in ARCH VGPRs
// (default heuristic capped at 80 arch -> acc spilled to AGPRs, 3x inst).
extern "C" __global__ void __launch_bounds__(320, 3)
energy_kernel(const float* __restrict__ orientation, const float* __restrict__ n_or,
              const float* __restrict__ W0T, const float* __restrict__ b0,
              const float* __restrict__ W1, const float* __restrict__ b1,
              const float* __restrict__ W2, const float* __restrict__ b2v,
              const float* __restrict__ f1, const float* __restrict__ f2,
              const float* __restrict__ ws_R, const float* __restrict__ ws_fc,
              const float* __restrict__ ws_F, const int* __restrict__ ws_idx,
              const float* __restrict__ ws_ndn,
              float* __restrict__ out_force, float* __restrict__ out_torque,
              float* __restrict__ out_energy)
{
    __shared__ float p_s[320];
    __shared__ float red[320][12];
    __shared__ float G[16][12];

    const int t = threadIdx.x;
    const int bl = t / 20;      // local b (0..15)
    const int n  = t % 20;      // selected-neighbor slot
    const int b  = blockIdx.x * 16 + bl;
    const size_t o = (size_t)b * NSEL + n;

    const float R  = ws_R[o];
    const float fc = ws_fc[o];
    const float F  = ws_F[b];
    const int  idx = ws_idx[o];
    const float nd0 = ws_ndn[o * 3 + 0];
    const float nd1 = ws_ndn[o * 3 + 1];
    const float nd2 = ws_ndn[o * 3 + 2];

    // feat = [dr_o(3), dr_no(3), o_no(9)]; O/Nr scoped so they die here.
    float feat[15];
    {
        float O[9], Nr[9];
        const float* Op = orientation + (size_t)b * 9;
        #pragma unroll
        for (int i = 0; i < 9; ++i) O[i] = Op[i];
        const float* Np = n_or + ((size_t)b * NB + idx) * 9;
        #pragma unroll
        for (int i = 0; i < 9; ++i) Nr[i] = Np[i];

        #pragma unroll
        for (int h = 0; h < 3; ++h)
            feat[h] = nd0 * O[h] + nd1 * O[3 + h] + nd2 * O[6 + h];
        #pragma unroll
        for (int h = 0; h < 3; ++h)
            feat[3 + h] = nd0 * Nr[h] + nd1 * Nr[3 + h] + nd2 * Nr[6 + h];
        #pragma unroll
        for (int l = 0; l < 3; ++l)
            #pragma unroll
            for (int m = 0; m < 3; ++m)
                feat[6 + l * 3 + m] = O[l] * Nr[m] + O[3 + l] * Nr[3 + m] + O[6 + l] * Nr[6 + m];
    }

    // ---------- forward ----------
    float acc[64];                      // z2 accumulators -> h2 -> dz2 (in place)
    #pragma unroll
    for (int i = 0; i < 64; ++i) acc[i] = b1[i];

    for (int j = 0; j < 64; ++j) {      // stream h1, never stored
        const float* w0r = W0T + j * 15;
        float z1 = b0[j];
        #pragma unroll
        for (int k = 0; k < 15; ++k) z1 = fmaf(feat[k], w0r[k], z1);
        float h1 = fast_tanh(z1);
        const float* w1r = W1 + j * 64;
        #pragma unroll
        for (int i = 0; i < 64; ++i) acc[i] = fmaf(h1, w1r[i], acc[i]);
    }

    float z3 = b2v[0];
    #pragma unroll
    for (int i = 0; i < 64; ++i) {
        acc[i] = fast_tanh(acc[i]);     // h2
        z3 = fmaf(acc[i], W2[i], z3);
    }
    const float enc = fast_tanh(z3);
    const float x = R - (enc * enc + EPSF);

    const float lx = __logf(x);
    float psum = 0.f, csum = 0.f;
    #pragma unroll
    for (int q = 0; q < 3; ++q) {
        float aq = f1[q] * f1[q] + EPSF;
        float cq = f2[q] * f2[q] + EPSF;
        float tq = __expf(-cq * (__logf(aq) + lx));   // (a*x)^(-c)
        psum += tq;
        csum = fmaf(cq, tq, csum);
    }
    const float dpdx = -__fdividef(csum, x);

    p_s[t] = psum;
    __syncthreads();
    float S = 0.f;
    for (int m = 0; m < 20; ++m) S += p_s[bl * 20 + m];
    out_energy[o] = S * fc;

    // ---------- backward ----------
    const float dz3 = F * dpdx * (-2.f * enc) * (1.f - enc * enc);
    #pragma unroll
    for (int i = 0; i < 64; ++i) {
        float h2 = acc[i];
        acc[i] = dz3 * W2[i] * (1.f - h2 * h2);   // dz2
    }

    float dfeat[15];
    #pragma unroll
    for (int k = 0; k < 15; ++k) dfeat[k] = 0.f;

    for (int j = 0; j < 64; ++j) {
        const float* w1r = W1 + j * 64;
        float s0 = 0.f, s1 = 0.f, s2 = 0.f, s3 = 0.f;   // 4-way split reduction
        #pragma unroll
        for (int i = 0; i < 64; i += 4) {
            s0 = fmaf(acc[i],     w1r[i],     s0);
            s1 = fmaf(acc[i + 1], w1r[i + 1], s1);
            s2 = fmaf(acc[i + 2], w1r[i + 2], s2);
            s3 = fmaf(acc[i + 3], w1r[i + 3], s3);
        }
        float dh1 = (s0 + s1) + (s2 + s3);
        const float* w0r = W0T + j * 15;
        float z1 = b0[j];                                // recompute h1
        #pragma unroll
        for (int k = 0; k < 15; ++k) z1 = fmaf(feat[k], w0r[k], z1);
        float h1 = fast_tanh(z1);
        float dz1 = dh1 * (1.f - h1 * h1);
        #pragma unroll
        for (int k = 0; k < 15; ++k) dfeat[k] = fmaf(dz1, w0r[k], dfeat[k]);
    }

    // ---- epilogue: reload O/Nr (volatile: keep live ranges short above) ----
    float O[9], Nr[9];
    {
        const volatile float* Ov = orientation + (size_t)b * 9;
        const volatile float* Nv = n_or + ((size_t)b * NB + idx) * 9;
        #pragma unroll
        for (int i = 0; i < 9; ++i) O[i] = Ov[i];
        #pragma unroll
        for (int i = 0; i < 9; ++i) Nr[i] = Nv[i];
    }

    float gdr[3];
    #pragma unroll
    for (int k = 0; k < 3; ++k)
        gdr[k] = dfeat[0] * O[k * 3] + dfeat[1] * O[k * 3 + 1] + dfeat[2] * O[k * 3 + 2]
               + dfeat[3] * Nr[k * 3] + dfeat[4] * Nr[k * 3 + 1] + dfeat[5] * Nr[k * 3 + 2];

    float ndv[3] = {nd0, nd1, nd2};
    float gO[9];
    #pragma unroll
    for (int k = 0; k < 3; ++k)
        #pragma unroll
        for (int h = 0; h < 3; ++h)
            gO[k * 3 + h] = dfeat[h] * ndv[k];      // from dr_o
    #pragma unroll
    for (int h = 0; h < 3; ++h)
        #pragma unroll
        for (int l = 0; l < 3; ++l) {
            float s = 0.f;                          // from o_no
            #pragma unroll
            for (int m = 0; m < 3; ++m) s = fmaf(dfeat[6 + l * 3 + m], Nr[h * 3 + m], s);
            gO[h * 3 + l] += s;
        }

    #pragma unroll
    for (int q = 0; q < 3; ++q) red[t][q] = gdr[q];
    #pragma unroll
    for (int q = 0; q < 9; ++q) red[t][3 + q] = gO[q];
    __syncthreads();

    for (int i = t; i < 16 * 12; i += 320) {
        int bb = i / 12, q = i % 12;
        float s = 0.f;
        for (int m = 0; m < 20; ++m) s += red[bb * 20 + m][q];
        G[bb][q] = s;
    }
    __syncthreads();

    if (t < 16) {
        const int gb = blockIdx.x * 16 + t;
        out_force[gb * 3 + 0] = G[t][0];
        out_force[gb * 3 + 1] = G[t][1];
        out_force[gb * 3 + 2] = G[t][2];
        const float* Og = orientation + (size_t)gb * 9;
        float t0 = 0.f, t1 = 0.f, t2 = 0.f;
        #pragma unroll
        for (int jj = 0; jj < 3; ++jj) {
            float u0 = G[t][3 + 0 * 3 + jj], u1 = G[t][3 + 1 * 3 + jj], u2 = G[t][3 + 2 * 3 + jj];
            float v0 = Og[0 * 3 + jj], v1 = Og[1 * 3 + jj], v2 = Og[2 * 3 + jj];
            t0 += u1 * v2 - u2 * v1;
            t1 += u2 * v0 - u0 * v2;
            t2 += u0 * v1 - u1 * v0;
        }
        out_torque[gb * 3 + 0] = t0;
        out_torque[gb * 3 + 1] = t1;
        out_torque[gb * 3 + 2] = t2;
    }
}

extern "C" void kernel_launch(void* const* d_in, const int* in_sizes, int n_in,
                              void* d_out, int out_size, void* d_ws, size_t ws_size,
                              hipStream_t stream) {
    const float* dr            = (const float*)d_in[0];
    const float* orientation   = (const float*)d_in[1];
    const float* n_orientation = (const float*)d_in[2];
    const float* W0 = (const float*)d_in[3];
    const float* b0 = (const float*)d_in[4];
    const float* W1 = (const float*)d_in[5];
    const float* b1 = (const float*)d_in[6];
    const float* W2 = (const float*)d_in[7];
    const float* b2 = (const float*)d_in[8];
    const float* f1 = (const float*)d_in[9];
    const float* f2 = (const float*)d_in[10];

    const int B = in_sizes[0] / (NB * 3);   // 32768

    float* out = (float*)d_out;
    float* out_force  = out;
    float* out_torque = out + (size_t)3 * B;
    float* out_energy = out + (size_t)6 * B;

    float* ws_R   = (float*)d_ws;                       // B*20
    float* ws_fc  = ws_R  + (size_t)B * NSEL;           // B*20
    float* ws_F   = ws_fc + (size_t)B * NSEL;           // B
    int*   ws_idx = (int*)(ws_F + B);                   // B*20
    float* ws_ndn = (float*)(ws_idx + (size_t)B * NSEL);// B*20*3
    float* ws_W0T = ws_ndn + (size_t)B * NSEL * 3;      // 960

    sel_kernel<<<B / 4, 256, 0, stream>>>(dr, W0, ws_R, ws_fc, ws_F, ws_idx, ws_ndn, ws_W0T);
    energy_kernel<<<B / 16, 320, 0, stream>>>(orientation, n_orientation,
                                              ws_W0T, b0, W1, b1, W2, b2, f1, f2,
                                              ws_R, ws_fc, ws_F, ws_idx, ws_ndn,
                                              out_force, out_torque, out_energy);
}

// Round 5
// 498.756 us; speedup vs baseline: 4.0976x; 1.2968x over previous
//
#include <hip/hip_runtime.h>

#define EPSF 1e-8f
#define RCUT 4.8f
#define NB 64
#define NSEL 20

__device__ __forceinline__ float fast_tanh(float x) {
    float e = __expf(2.0f * x);
    return 1.0f - __fdividef(2.0f, e + 1.0f);
}

// ---------------- Kernel A: norms + select 20 nearest (sorted) ----------------
extern "C" __global__ void __launch_bounds__(256)
sel_kernel(const float* __restrict__ dr, const float* __restrict__ W0,
           float* __restrict__ ws_R, float* __restrict__ ws_fc,
           float* __restrict__ ws_F, int* __restrict__ ws_idx,
           float* __restrict__ ws_ndn, float* __restrict__ ws_W0T)
{
    __shared__ float R_s[256];
    const int t = threadIdx.x;
    const int g = t >> 6;       // which b within block (0..3)
    const int j = t & 63;       // neighbor id
    const int b = blockIdx.x * 4 + g;

    const float* p = dr + ((size_t)b * NB + j) * 3;
    float x = p[0] + EPSF, y = p[1] + EPSF, z = p[2] + EPSF;
    float R = sqrtf(x * x + y * y + z * z);
    R_s[t] = R;
    __syncthreads();

    // stable rank: count (Rk < R) or (Rk == R and k < j)
    int rank = 0;
    const float* grp = R_s + g * 64;
    #pragma unroll 8
    for (int k = 0; k < 64; ++k) {
        float Rk = grp[k];
        rank += (Rk < R || (Rk == R && k < j)) ? 1 : 0;
    }

    float fc = 0.0f;
    if (rank < NSEL) {
        fc = (R > RCUT) ? 0.0f
                        : (0.5f * __cosf(3.14159265358979323846f * R / RCUT) + 0.5f);
        size_t o = (size_t)b * NSEL + rank;
        ws_R[o]  = R;
        ws_fc[o] = fc;
        ws_idx[o] = j;
        float inv = 1.0f / R;
        ws_ndn[o * 3 + 0] = x * inv;
        ws_ndn[o * 3 + 1] = y * inv;
        ws_ndn[o * 3 + 2] = z * inv;
    }

    // F[b] = sum of selected fc over this wave (each group is exactly one wave)
    float F = fc;
    for (int off = 32; off > 0; off >>= 1) F += __shfl_xor(F, off, 64);
    if (j == 0) ws_F[b] = F;

    // one-time W0 transpose (block 0 only; A always runs before B on the stream)
    if (blockIdx.x == 0) {
        for (int i = t; i < 15 * 64; i += 256) {
            int k = i >> 6, jj = i & 63;
            ws_W0T[jj * 15 + k] = W0[i];
        }
    }
}

// ---------------- Kernel B: per-pair MLP fwd + analytic bwd ----------------
// (320,4): cap 128 total regs/wave (acc[64] in AGPRs + <=64 arch) so 3 blocks/CU
// co-reside (R4 ran 1 block/CU = 1.25 waves/SIMD -> VALUBusy 34%).
// Scalars R/fc/F/nd/idx are re-loaded volatile at use sites to keep arch
// live range <= 64 through the hot loops.
extern "C" __global__ void __launch_bounds__(320, 4)
energy_kernel(const float* __restrict__ orientation, const float* __restrict__ n_or,
              const float* __restrict__ W0T, const float* __restrict__ b0,
              const float* __restrict__ W1, const float* __restrict__ b1,
              const float* __restrict__ W2, const float* __restrict__ b2v,
              const float* __restrict__ f1, const float* __restrict__ f2,
              const float* __restrict__ ws_R, const float* __restrict__ ws_fc,
              const float* __restrict__ ws_F, const int* __restrict__ ws_idx,
              const float* __restrict__ ws_ndn,
              float* __restrict__ out_force, float* __restrict__ out_torque,
              float* __restrict__ out_energy)
{
    __shared__ float p_s[320];
    __shared__ float red[320][12];
    __shared__ float G[16][12];

    const int t = threadIdx.x;
    const int bl = t / 20;      // local b (0..15)
    const int n  = t % 20;      // selected-neighbor slot
    const int b  = blockIdx.x * 16 + bl;
    const size_t o = (size_t)b * NSEL + n;

    // feat = [dr_o(3), dr_no(3), o_no(9)]; O/Nr/nd scoped so they die here.
    float feat[15];
    {
        const float nd0 = ws_ndn[o * 3 + 0];
        const float nd1 = ws_ndn[o * 3 + 1];
        const float nd2 = ws_ndn[o * 3 + 2];
        const int  idx = ws_idx[o];
        float O[9], Nr[9];
        const float* Op = orientation + (size_t)b * 9;
        #pragma unroll
        for (int i = 0; i < 9; ++i) O[i] = Op[i];
        const float* Np = n_or + ((size_t)b * NB + idx) * 9;
        #pragma unroll
        for (int i = 0; i < 9; ++i) Nr[i] = Np[i];

        #pragma unroll
        for (int h = 0; h < 3; ++h)
            feat[h] = nd0 * O[h] + nd1 * O[3 + h] + nd2 * O[6 + h];
        #pragma unroll
        for (int h = 0; h < 3; ++h)
            feat[3 + h] = nd0 * Nr[h] + nd1 * Nr[3 + h] + nd2 * Nr[6 + h];
        #pragma unroll
        for (int l = 0; l < 3; ++l)
            #pragma unroll
            for (int m = 0; m < 3; ++m)
                feat[6 + l * 3 + m] = O[l] * Nr[m] + O[3 + l] * Nr[3 + m] + O[6 + l] * Nr[6 + m];
    }

    // ---------- forward (j, j+1 interleaved for 2x ILP on the serial chain) ----
    float acc[64];                      // z2 accumulators -> h2 -> dz2 (in place)
    #pragma unroll
    for (int i = 0; i < 64; ++i) acc[i] = b1[i];

    for (int j = 0; j < 64; j += 2) {
        const float* w0a = W0T + j * 15;
        const float* w0b = w0a + 15;
        float za = b0[j], zb = b0[j + 1];
        #pragma unroll
        for (int k = 0; k < 15; ++k) {
            za = fmaf(feat[k], w0a[k], za);
            zb = fmaf(feat[k], w0b[k], zb);
        }
        float ha = fast_tanh(za), hb = fast_tanh(zb);
        const float* w1a = W1 + j * 64;
        const float* w1b = w1a + 64;
        #pragma unroll
        for (int i = 0; i < 64; ++i)
            acc[i] = fmaf(hb, w1b[i], fmaf(ha, w1a[i], acc[i]));
    }

    // ---------- h2, z3 (4 partial sums) ----------
    float z30 = b2v[0], z31 = 0.f, z32 = 0.f, z33 = 0.f;
    #pragma unroll
    for (int i = 0; i < 64; i += 4) {
        acc[i]     = fast_tanh(acc[i]);
        acc[i + 1] = fast_tanh(acc[i + 1]);
        acc[i + 2] = fast_tanh(acc[i + 2]);
        acc[i + 3] = fast_tanh(acc[i + 3]);
        z30 = fmaf(acc[i],     W2[i],     z30);
        z31 = fmaf(acc[i + 1], W2[i + 1], z31);
        z32 = fmaf(acc[i + 2], W2[i + 2], z32);
        z33 = fmaf(acc[i + 3], W2[i + 3], z33);
    }
    const float enc = fast_tanh((z30 + z31) + (z32 + z33));
    float x;
    {
        const volatile float* Rv = ws_R + o;    // late load: don't hold R
        x = Rv[0] - (enc * enc + EPSF);
    }

    const float lx = __logf(x);
    float psum = 0.f, csum = 0.f;
    #pragma unroll
    for (int q = 0; q < 3; ++q) {
        float aq = f1[q] * f1[q] + EPSF;
        float cq = f2[q] * f2[q] + EPSF;
        float tq = __expf(-cq * (__logf(aq) + lx));   // (a*x)^(-c)
        psum += tq;
        csum = fmaf(cq, tq, csum);
    }
    const float dpdx = -__fdividef(csum, x);

    p_s[t] = psum;
    __syncthreads();
    {
        float S = 0.f;
        for (int m = 0; m < 20; ++m) S += p_s[bl * 20 + m];
        const volatile float* fcv = ws_fc + o;  // late load: don't hold fc
        out_energy[o] = S * fcv[0];
    }

    // ---------- backward ----------
    float dz3;
    {
        const volatile float* Fv = ws_F + b;    // late load: don't hold F
        dz3 = Fv[0] * dpdx * (-2.f * enc) * (1.f - enc * enc);
    }
    #pragma unroll
    for (int i = 0; i < 64; ++i) {
        float h2 = acc[i];
        acc[i] = dz3 * W2[i] * (1.f - h2 * h2);   // dz2
    }

    float dfeat[15];
    #pragma unroll
    for (int k = 0; k < 15; ++k) dfeat[k] = 0.f;

    for (int j = 0; j < 64; j += 2) {
        const float* w1a = W1 + j * 64;
        const float* w1b = w1a + 64;
        float sa0 = 0.f, sa1 = 0.f, sb0 = 0.f, sb1 = 0.f;
        #pragma unroll
        for (int i = 0; i < 64; i += 2) {
            sa0 = fmaf(acc[i],     w1a[i],     sa0);
            sa1 = fmaf(acc[i + 1], w1a[i + 1], sa1);
            sb0 = fmaf(acc[i],     w1b[i],     sb0);
            sb1 = fmaf(acc[i + 1], w1b[i + 1], sb1);
        }
        float dha = sa0 + sa1, dhb = sb0 + sb1;
        const float* w0a = W0T + j * 15;
        const float* w0b = w0a + 15;
        float za = b0[j], zb = b0[j + 1];               // recompute h1 pair
        #pragma unroll
        for (int k = 0; k < 15; ++k) {
            za = fmaf(feat[k], w0a[k], za);
            zb = fmaf(feat[k], w0b[k], zb);
        }
        float ha = fast_tanh(za), hb = fast_tanh(zb);
        float dza = dha * (1.f - ha * ha);
        float dzb = dhb * (1.f - hb * hb);
        #pragma unroll
        for (int k = 0; k < 15; ++k)
            dfeat[k] = fmaf(dzb, w0b[k], fmaf(dza, w0a[k], dfeat[k]));
    }

    // ---- epilogue: reload O/Nr/nd (volatile: keep live ranges short above) ----
    float O[9], Nr[9], nd0, nd1, nd2;
    {
        const volatile int* iv = ws_idx + o;
        const int idx = iv[0];
        const volatile float* Ov = orientation + (size_t)b * 9;
        const volatile float* Nv = n_or + ((size_t)b * NB + idx) * 9;
        #pragma unroll
        for (int i = 0; i < 9; ++i) O[i] = Ov[i];
        #pragma unroll
        for (int i = 0; i < 9; ++i) Nr[i] = Nv[i];
        const volatile float* nv = ws_ndn + o * 3;
        nd0 = nv[0]; nd1 = nv[1]; nd2 = nv[2];
    }

    float gdr[3];
    #pragma unroll
    for (int k = 0; k < 3; ++k)
        gdr[k] = dfeat[0] * O[k * 3] + dfeat[1] * O[k * 3 + 1] + dfeat[2] * O[k * 3 + 2]
               + dfeat[3] * Nr[k * 3] + dfeat[4] * Nr[k * 3 + 1] + dfeat[5] * Nr[k * 3 + 2];

    float ndv[3] = {nd0, nd1, nd2};
    float gO[9];
    #pragma unroll
    for (int k = 0; k < 3; ++k)
        #pragma unroll
        for (int h = 0; h < 3; ++h)
            gO[k * 3 + h] = dfeat[h] * ndv[k];      // from dr_o
    #pragma unroll
    for (int h = 0; h < 3; ++h)
        #pragma unroll
        for (int l = 0; l < 3; ++l) {
            float s = 0.f;                          // from o_no
            #pragma unroll
            for (int m = 0; m < 3; ++m) s = fmaf(dfeat[6 + l * 3 + m], Nr[h * 3 + m], s);
            gO[h * 3 + l] += s;
        }

    #pragma unroll
    for (int q = 0; q < 3; ++q) red[t][q] = gdr[q];
    #pragma unroll
    for (int q = 0; q < 9; ++q) red[t][3 + q] = gO[q];
    __syncthreads();

    for (int i = t; i < 16 * 12; i += 320) {
        int bb = i / 12, q = i % 12;
        float s = 0.f;
        for (int m = 0; m < 20; ++m) s += red[bb * 20 + m][q];
        G[bb][q] = s;
    }
    __syncthreads();

    if (t < 16) {
        const int gb = blockIdx.x * 16 + t;
        out_force[gb * 3 + 0] = G[t][0];
        out_force[gb * 3 + 1] = G[t][1];
        out_force[gb * 3 + 2] = G[t][2];
        const float* Og = orientation + (size_t)gb * 9;
        float t0 = 0.f, t1 = 0.f, t2 = 0.f;
        #pragma unroll
        for (int jj = 0; jj < 3; ++jj) {
            float u0 = G[t][3 + 0 * 3 + jj], u1 = G[t][3 + 1 * 3 + jj], u2 = G[t][3 + 2 * 3 + jj];
            float v0 = Og[0 * 3 + jj], v1 = Og[1 * 3 + jj], v2 = Og[2 * 3 + jj];
            t0 += u1 * v2 - u2 * v1;
            t1 += u2 * v0 - u0 * v2;
            t2 += u0 * v1 - u1 * v0;
        }
        out_torque[gb * 3 + 0] = t0;
        out_torque[gb * 3 + 1] = t1;
        out_torque[gb * 3 + 2] = t2;
    }
}

extern "C" void kernel_launch(void* const* d_in, const int* in_sizes, int n_in,
                              void* d_out, int out_size, void* d_ws, size_t ws_size,
                              hipStream_t stream) {
    const float* dr            = (const float*)d_in[0];
    const float* orientation   = (const float*)d_in[1];
    const float* n_orientation = (const float*)d_in[2];
    const float* W0 = (const float*)d_in[3];
    const float* b0 = (const float*)d_in[4];
    const float* W1 = (const float*)d_in[5];
    const float* b1 = (const float*)d_in[6];
    const float* W2 = (const float*)d_in[7];
    const float* b2 = (const float*)d_in[8];
    const float* f1 = (const float*)d_in[9];
    const float* f2 = (const float*)d_in[10];

    const int B = in_sizes[0] / (NB * 3);   // 32768

    float* out = (float*)d_out;
    float* out_force  = out;
    float* out_torque = out + (size_t)3 * B;
    float* out_energy = out + (size_t)6 * B;

    float* ws_R   = (float*)d_ws;                       // B*20
    float* ws_fc  = ws_R  + (size_t)B * NSEL;           // B*20
    float* ws_F   = ws_fc + (size_t)B * NSEL;           // B
    int*   ws_idx = (int*)(ws_F + B);                   // B*20
    float* ws_ndn = (float*)(ws_idx + (size_t)B * NSEL);// B*20*3
    float* ws_W0T = ws_ndn + (size_t)B * NSEL * 3;      // 960

    sel_kernel<<<B / 4, 256, 0, stream>>>(dr, W0, ws_R, ws_fc, ws_F, ws_idx, ws_ndn, ws_W0T);
    energy_kernel<<<B / 16, 320, 0, stream>>>(orientation, n_orientation,
                                              ws_W0T, b0, W1, b1, W2, b2, f1, f2,
                                              ws_R, ws_fc, ws_F, ws_idx, ws_ndn,
                                              out_force, out_torque, out_energy);
}